// Round 6
// baseline (304.742 us; speedup 1.0000x reference)
//
#include <hip/hip_runtime.h>
#include <hip/hip_bf16.h>
#include <math.h>

#define L 2048
#define D 256

typedef __attribute__((ext_vector_type(8))) short bf16x8;
typedef __attribute__((ext_vector_type(4))) float f32x4;
typedef __attribute__((ext_vector_type(4))) int i32x4;

__device__ __forceinline__ unsigned short f2bf(float f) {
    union { float f; unsigned int u; } v; v.f = f;
    unsigned int r = v.u + 0x7FFFu + ((v.u >> 16) & 1u);   // RNE
    return (unsigned short)(r >> 16);
}

// --- transpose Wv, Wo (f32 k-major) -> bf16 n-major ---------------------
__global__ __launch_bounds__(256) void wtrans_kernel(
    const float* __restrict__ Wv, const float* __restrict__ Wo,
    unsigned short* __restrict__ Wvt, unsigned short* __restrict__ Wot) {
    int idx = blockIdx.x * 256 + threadIdx.x;       // 0..131071
    int which = idx >> 16;
    int e = idx & 65535;
    int n = e >> 8, k = e & 255;
    const float* W = which ? Wo : Wv;
    unsigned short* Wt = which ? Wot : Wvt;
    Wt[n * 256 + k] = f2bf(W[k * 256 + n]);
}

// --- LDS-free GEMM: v = value @ Wv + bv, stored TRANSPOSED bf16 Vt[b][n][j]
__global__ __launch_bounds__(256) void gemm_v_kernel(
    const float* __restrict__ A,
    const unsigned short* __restrict__ Wt,   // [256][256] bf16 n-major
    const float* __restrict__ bias,
    unsigned short* __restrict__ Vt) {
    const int wave = threadIdx.x >> 6;
    const int lane = threadIdx.x & 63;
    const int mh = wave >> 1, nh = wave & 1;
    const int lm = lane & 15, q = lane >> 4;
    const int m0 = blockIdx.x * 64;
    const int n0 = blockIdx.y * 128;

    f32x4 acc[2][4];
#pragma unroll
    for (int i = 0; i < 2; i++)
#pragma unroll
        for (int j = 0; j < 4; j++) acc[i][j] = (f32x4)(0.f);

    int arow[2];
    arow[0] = m0 + mh * 32 + lm;
    arow[1] = arow[0] + 16;
    int ncol[4];
#pragma unroll
    for (int nf = 0; nf < 4; nf++) ncol[nf] = n0 + nh * 64 + nf * 16 + lm;

    for (int k0 = 0; k0 < 256; k0 += 32) {
        int kq = k0 + q * 8;
        bf16x8 bfr[4];
#pragma unroll
        for (int nf = 0; nf < 4; nf++)
            bfr[nf] = *reinterpret_cast<const bf16x8*>(Wt + ncol[nf] * 256 + kq);
        bf16x8 afr[2];
#pragma unroll
        for (int mf = 0; mf < 2; mf++) {
            const float* ap = A + arow[mf] * 256 + kq;
            f32x4 a0 = *reinterpret_cast<const f32x4*>(ap);
            f32x4 a1 = *reinterpret_cast<const f32x4*>(ap + 4);
            bf16x8 t;
#pragma unroll
            for (int e = 0; e < 4; e++) t[e] = (short)f2bf(a0[e]);
#pragma unroll
            for (int e = 0; e < 4; e++) t[4 + e] = (short)f2bf(a1[e]);
            afr[mf] = t;
        }
#pragma unroll
        for (int mf = 0; mf < 2; mf++)
#pragma unroll
            for (int nf = 0; nf < 4; nf++)
                acc[mf][nf] = __builtin_amdgcn_mfma_f32_16x16x32_bf16(
                    afr[mf], bfr[nf], acc[mf][nf], 0, 0, 0);
    }

#pragma unroll
    for (int mf = 0; mf < 2; mf++) {
        int mrow = m0 + mh * 32 + mf * 16 + q * 4;   // rows mrow..mrow+3
#pragma unroll
        for (int nf = 0; nf < 4; nf++) {
            int n = ncol[nf];
            float bias_n = bias[n];
            int b = mrow >> 11;
            int j = mrow & 2047;
            unsigned short* dst = Vt + (size_t)b * (D * L) + (size_t)n * L + j;
            ushort4 pk;
            pk.x = f2bf(acc[mf][nf][0] + bias_n);
            pk.y = f2bf(acc[mf][nf][1] + bias_n);
            pk.z = f2bf(acc[mf][nf][2] + bias_n);
            pk.w = f2bf(acc[mf][nf][3] + bias_n);
            *reinterpret_cast<ushort4*>(dst) = pk;
        }
    }
}

// --- PURE STREAMING, MAX MLP: all 12 loads issued before any use --------
// One wave per half-row (16384 waves). launch_bounds(256,4) -> 128 VGPR cap
// so the compiler cannot sink the loads: 12 outstanding 1KB loads per wave.
__global__ __launch_bounds__(256, 4) void p_kernel(
    const float* __restrict__ atten, const float* __restrict__ mask,
    const int* __restrict__ pad, unsigned short* __restrict__ P,
    float* __restrict__ lsum2) {
    const int wid = blockIdx.x * 4 + (threadIdx.x >> 6);   // 0..16383
    const int row = wid >> 1, h = wid & 1;
    const int lane = threadIdx.x & 63;

    const size_t base = (size_t)row * L + h * 1024 + lane * 4;
    const float* at = atten + base;
    const float* mk = mask  + base;
    const int*   pd = pad   + base;
    unsigned short* Pr = P + base;

    f32x4 a[4], m[4]; i32x4 p[4];
#pragma unroll
    for (int c = 0; c < 4; c++) a[c] = *reinterpret_cast<const f32x4*>(at + c * 256);
#pragma unroll
    for (int c = 0; c < 4; c++) m[c] = *reinterpret_cast<const f32x4*>(mk + c * 256);
#pragma unroll
    for (int c = 0; c < 4; c++) p[c] = *reinterpret_cast<const i32x4*>(pd + c * 256);

    float l_th = 0.f;
#pragma unroll
    for (int c = 0; c < 4; c++) {
        ushort4 pk;
        float pv;
        pv = (m[c][0] < 0.5f || p[c][0] == 0) ? 0.f : __expf(a[c][0]); l_th += pv; pk.x = f2bf(pv);
        pv = (m[c][1] < 0.5f || p[c][1] == 0) ? 0.f : __expf(a[c][1]); l_th += pv; pk.y = f2bf(pv);
        pv = (m[c][2] < 0.5f || p[c][2] == 0) ? 0.f : __expf(a[c][2]); l_th += pv; pk.z = f2bf(pv);
        pv = (m[c][3] < 0.5f || p[c][3] == 0) ? 0.f : __expf(a[c][3]); l_th += pv; pk.w = f2bf(pv);
        *reinterpret_cast<ushort4*>(Pr + c * 256) = pk;
    }
#pragma unroll
    for (int off = 1; off < 64; off <<= 1) l_th += __shfl_xor(l_th, off);
    if (lane == 0) lsum2[wid] = l_th;
}

// --- full-K GEMM T = P @ Vt^T (k=2048) + normalize + fused out-GEMM -----
// 512 blocks x 16 rows x full 256 n (2 blocks/CU, 8 waves/CU).
// k-loop barrier-free, register-pipelined, direct global frag loads
// (P k-contiguous from L3, Vt k-contiguous from L2). One sync at epilogue.
__global__ __launch_bounds__(256, 2) void pv_out_kernel(
    const unsigned short* __restrict__ P, const unsigned short* __restrict__ Vt,
    const float* __restrict__ lsum2, const unsigned short* __restrict__ Wot,
    const float* __restrict__ bo, float* __restrict__ out) {
    const int rb = blockIdx.x;          // 0..511 -> rows rb*16..+15
    const int tid = threadIdx.x;
    const int w = tid >> 6, lane = tid & 63;
    const int lm = lane & 15, q = lane >> 4;
    const int b = rb >> 7;
    const int row0 = rb * 16;

    const unsigned short* pA = P + (size_t)row0 * L + (size_t)lm * L + q * 8;
    const unsigned short* pB = Vt + (size_t)b * (D * L) + (size_t)(w * 64) * L + q * 8;

    f32x4 acc[4];
#pragma unroll
    for (int j = 0; j < 4; j++) acc[j] = (f32x4)(0.f);

    bf16x8 Ac[2], Bc[2][4], An[2], Bn[2][4];
#pragma unroll
    for (int kk = 0; kk < 2; kk++) {
        Ac[kk] = *reinterpret_cast<const bf16x8*>(pA + kk * 32);
#pragma unroll
        for (int nf = 0; nf < 4; nf++)
            Bc[kk][nf] = *reinterpret_cast<const bf16x8*>(pB + (nf * 16 + lm) * L + kk * 32);
    }

    for (int t = 0; t < 32; t++) {
        if (t < 31) {
            const int kn = (t + 1) * 64;
#pragma unroll
            for (int kk = 0; kk < 2; kk++) {
                An[kk] = *reinterpret_cast<const bf16x8*>(pA + kn + kk * 32);
#pragma unroll
                for (int nf = 0; nf < 4; nf++)
                    Bn[kk][nf] = *reinterpret_cast<const bf16x8*>(
                        pB + (nf * 16 + lm) * L + kn + kk * 32);
            }
        }
#pragma unroll
        for (int kk = 0; kk < 2; kk++)
#pragma unroll
            for (int nf = 0; nf < 4; nf++)
                acc[nf] = __builtin_amdgcn_mfma_f32_16x16x32_bf16(
                    Ac[kk], Bc[kk][nf], acc[nf], 0, 0, 0);
#pragma unroll
        for (int kk = 0; kk < 2; kk++) {
            Ac[kk] = An[kk];
#pragma unroll
            for (int nf = 0; nf < 4; nf++) Bc[kk][nf] = Bn[kk][nf];
        }
    }

    // normalize (÷l) and park T as bf16 in LDS (C-layout -> A-layout)
    __shared__ __align__(16) unsigned short Alds[16][264];
    float inv[4];
#pragma unroll
    for (int rg = 0; rg < 4; rg++) {
        int gr = row0 + q * 4 + rg;
        inv[rg] = 1.f / (lsum2[2 * gr] + lsum2[2 * gr + 1]);
    }
#pragma unroll
    for (int nf = 0; nf < 4; nf++) {
        int col = w * 64 + nf * 16 + lm;
#pragma unroll
        for (int rg = 0; rg < 4; rg++)
            Alds[q * 4 + rg][col] = f2bf(acc[nf][rg] * inv[rg]);
    }
    __syncthreads();

    // out = T @ Wo + bo   (16x256 @ 256x256, A from LDS, B = Wot global/L2)
    f32x4 oacc[4];
#pragma unroll
    for (int j = 0; j < 4; j++) oacc[j] = (f32x4)(0.f);
    int ncol[4];
#pragma unroll
    for (int nf = 0; nf < 4; nf++) ncol[nf] = w * 64 + nf * 16 + lm;

    for (int kk = 0; kk < 8; kk++) {
        int kq = kk * 32 + q * 8;
        bf16x8 bfr[4];
#pragma unroll
        for (int nf = 0; nf < 4; nf++)
            bfr[nf] = *reinterpret_cast<const bf16x8*>(Wot + ncol[nf] * 256 + kq);
        bf16x8 afr = *reinterpret_cast<const bf16x8*>(&Alds[lm][kq]);
#pragma unroll
        for (int nf = 0; nf < 4; nf++)
            oacc[nf] = __builtin_amdgcn_mfma_f32_16x16x32_bf16(
                afr, bfr[nf], oacc[nf], 0, 0, 0);
    }

    const int mrow = row0 + q * 4;
#pragma unroll
    for (int nf = 0; nf < 4; nf++) {
        int n = ncol[nf];
        float bn = bo[n];
#pragma unroll
        for (int rg = 0; rg < 4; rg++)
            out[(size_t)(mrow + rg) * 256 + n] = oacc[nf][rg] + bn;
    }
}

extern "C" void kernel_launch(void* const* d_in, const int* in_sizes, int n_in,
                              void* d_out, int out_size, void* d_ws, size_t ws_size,
                              hipStream_t stream) {
    (void)in_sizes; (void)n_in; (void)out_size; (void)ws_size;
    const float* atten = (const float*)d_in[0];
    const float* value = (const float*)d_in[1];
    const float* mask  = (const float*)d_in[2];
    const int*   pad   = (const int*)d_in[3];
    const float* Wv    = (const float*)d_in[4];
    const float* bv    = (const float*)d_in[5];
    const float* Wo    = (const float*)d_in[6];
    const float* bo    = (const float*)d_in[7];
    float* out = (float*)d_out;

    char* ws = (char*)d_ws;
    unsigned short* Vt  = (unsigned short*)(ws);              // 4 MB  bf16 [B][D][L]
    unsigned short* Wvt = (unsigned short*)(ws + 4194304);    // 128 KB
    unsigned short* Wot = (unsigned short*)(ws + 4325376);    // 128 KB
    unsigned short* P   = (unsigned short*)(ws + 4456448);    // 33.55 MB bf16 [8192][2048]
    float* lsum2        = (float*)(ws + 38010880);            // 64 KB

    wtrans_kernel<<<512, 256, 0, stream>>>(Wv, Wo, Wvt, Wot);
    gemm_v_kernel<<<dim3(128, 2), 256, 0, stream>>>(value, Wvt, bv, Vt);
    p_kernel<<<4096, 256, 0, stream>>>(atten, mask, pad, P, lsum2);
    pv_out_kernel<<<512, 256, 0, stream>>>(P, Vt, lsum2, Wot, bo, out);
}